// Round 10
// baseline (123.595 us; speedup 1.0000x reference)
//
#include <hip/hip_runtime.h>
#include <math.h>

#define N 8192
#define FIN 256
#define FOUT 64
#define ALPHA 0.2f
#define LOG2E 1.442695040888963f

#define JT 256                    // j-tile columns
#define NTILE (N / JT)            // 32
#define ROWPITCH 512              // bytes per A-LDS row (256 f16)
#define ABUF (16 * ROWPITCH)      // 8192 B per buffer
#define SMEM_BYTES (2 * ABUF)     // 16384 -> LDS no longer limits occupancy

typedef float f32x4 __attribute__((ext_vector_type(4)));
typedef _Float16 f16x8 __attribute__((ext_vector_type(8)));

union F16V { uint4 u; f16x8 h; };

__device__ __forceinline__ unsigned pack_f16(float a, float b) {
    union { _Float16 h; unsigned short u; } ca, cb;
    ca.h = (_Float16)a; cb.h = (_Float16)b;      // v_cvt_f16_f32, RNE
    return (unsigned)ca.u | ((unsigned)cb.u << 16);
}
// w' = exp(leaky(e)) * 2^-4  (scale cancels in softmax ratio; keeps f16 in range)
__device__ __forceinline__ float wcalc(int av, float fsr, float g) {
    float e = fsr + g;
    float le = e > 0.f ? e : ALPHA * e;
    float r = __builtin_exp2f(fmaf(le, LOG2E, -4.0f));
    return av != 0 ? r : 0.f;
}

// ---------------- Kernel 1: Wh = h@W -> fsrc/fdst + B_packed (pre-fragmented f16) ----
// Bp[(chunk*4+ft)*64 + lane] = f16(Wh[chunk*32+(lane>>4)*8+e][ft*16+(lane&15)])
// so gat_main's B-fragment loads are single contiguous 16B/lane segments.
__global__ __launch_bounds__(512) void gat_prep(
    const float* __restrict__ h, const float* __restrict__ W,
    const float* __restrict__ a,
    float* __restrict__ fsrc, float* __restrict__ fdst,
    uint4* __restrict__ Bp)
{
    __shared__ float sWh[32][FOUT + 1];
    const int t = threadIdx.x;
    const int f = t & 63;
    const int wq = t >> 6;                 // 0..7, 4 rows each
    const int row0 = blockIdx.x * 32;
    const int rbase = row0 + wq * 4;

    float acc[4] = {0.f, 0.f, 0.f, 0.f};
    for (int k0 = 0; k0 < FIN; k0 += 4) {
        const float w0 = W[(k0 + 0) * FOUT + f];
        const float w1 = W[(k0 + 1) * FOUT + f];
        const float w2 = W[(k0 + 2) * FOUT + f];
        const float w3 = W[(k0 + 3) * FOUT + f];
#pragma unroll
        for (int rr = 0; rr < 4; ++rr) {
            const float4 hv = *reinterpret_cast<const float4*>(
                &h[(size_t)(rbase + rr) * FIN + k0]);
            acc[rr] = fmaf(hv.x, w0, acc[rr]);
            acc[rr] = fmaf(hv.y, w1, acc[rr]);
            acc[rr] = fmaf(hv.z, w2, acc[rr]);
            acc[rr] = fmaf(hv.w, w3, acc[rr]);
        }
    }
    const float as = a[f], ad = a[FOUT + f];
#pragma unroll
    for (int rr = 0; rr < 4; ++rr) {
        sWh[wq * 4 + rr][f] = acc[rr];
        float fs = acc[rr] * as, fd = acc[rr] * ad;
#pragma unroll
        for (int off = 1; off < 64; off <<= 1) {
            fs += __shfl_xor(fs, off, 64);
            fd += __shfl_xor(fd, off, 64);
        }
        if (f == 0) { fsrc[rbase + rr] = fs; fdst[rbase + rr] = fd; }
    }
    __syncthreads();
    if (t < 256) {
        const int ft = t >> 6;             // 0..3
        const int l = t & 63;
        const int li = l & 15, g = l >> 4;
        float v[8];
#pragma unroll
        for (int e = 0; e < 8; ++e) v[e] = sWh[g * 8 + e][ft * 16 + li];
        uint4 pk;
        pk.x = pack_f16(v[0], v[1]);
        pk.y = pack_f16(v[2], v[3]);
        pk.z = pack_f16(v[4], v[5]);
        pk.w = pack_f16(v[6], v[7]);
        Bp[(size_t)(blockIdx.x * 4 + ft) * 64 + l] = pk;
    }
}

// ---------------- Kernel 2: A-only-LDS MFMA flash softmax-PV ----
// adj read contiguously (R5/R7 lesson), redistributed to A-fragment layout via
// a small dbuf LDS tile; B fragments loaded coalesced from Bp (R8 lesson, no
// LDS). Raw s_barrier + lgkmcnt(0)-only waits -> register prefetches survive
// barriers with counted vmcnt. 16KB LDS.
struct AdjG { int4 a0, a1; float4 g0, g1; };

__global__ __launch_bounds__(512, 6) void gat_main(
    const int* __restrict__ adj,
    const uint4* __restrict__ Bp,
    const float* __restrict__ fsrc, const float* __restrict__ fdst,
    float* __restrict__ out)
{
    __shared__ __align__(16) char smem[SMEM_BYTES];

    const int t = threadIdx.x;
    const int l = t & 63;
    const int w = t >> 6;
    const int row0 = blockIdx.x * 16;

    // --- staging map (contiguous adj) ---
    const int srow = t >> 5;               // 0..15
    const int sc8 = (t & 31) * 8;          // col (elements)
    const float fsr = fsrc[row0 + srow];
    const size_t adjrow = (size_t)(row0 + srow) * N;
    const int awo = srow * ROWPITCH + (((t & 31) * 16) ^ ((srow & 7) << 4));

    // --- MFMA map ---
    const int ft = w & 3;
    const int p = w >> 2;
    const int r16 = l & 15;
    const int kg8 = (l >> 4) << 3;
    const int fswz = (r16 & 7) << 4;
    const int aro = r16 * ROWPITCH;
    // Bp index (uint4): tile*2048 + p*1024 + ks*256 + ft*64 + lane
    const uint4* Bq = Bp + (size_t)p * 1024 + ft * 64 + l;

    f32x4 acc = {0.f, 0.f, 0.f, 0.f};
    float zacc = 0.f;
    AdjG AG;
    uint4 BA0, BA1, BA2, BA3, BB0, BB1, BB2, BB3;

#define BAR                                                                    \
    {                                                                          \
        asm volatile("s_waitcnt lgkmcnt(0)" ::: "memory");                     \
        __builtin_amdgcn_s_barrier();                                          \
    }

#define LOAD_ADJG(tile)                                                        \
    {                                                                          \
        const int j0_ = (tile) * JT;                                           \
        AG.a0 = *reinterpret_cast<const int4*>(&adj[adjrow + j0_ + sc8]);      \
        AG.a1 = *reinterpret_cast<const int4*>(&adj[adjrow + j0_ + sc8 + 4]);  \
        AG.g0 = *reinterpret_cast<const float4*>(&fdst[j0_ + sc8]);            \
        AG.g1 = *reinterpret_cast<const float4*>(&fdst[j0_ + sc8 + 4]);        \
    }

#define LOAD_B(tile, B0, B1, B2, B3)                                           \
    {                                                                          \
        const uint4* bq_ = Bq + (size_t)(tile) * 2048;                         \
        B0 = bq_[0];                                                           \
        B1 = bq_[256];                                                         \
        B2 = bq_[512];                                                         \
        B3 = bq_[768];                                                         \
    }

#define STAGE(BUF)                                                             \
    {                                                                          \
        const float w0 = wcalc(AG.a0.x, fsr, AG.g0.x);                         \
        const float w1 = wcalc(AG.a0.y, fsr, AG.g0.y);                         \
        const float w2 = wcalc(AG.a0.z, fsr, AG.g0.z);                         \
        const float w3 = wcalc(AG.a0.w, fsr, AG.g0.w);                         \
        const float w4 = wcalc(AG.a1.x, fsr, AG.g1.x);                         \
        const float w5 = wcalc(AG.a1.y, fsr, AG.g1.y);                         \
        const float w6 = wcalc(AG.a1.z, fsr, AG.g1.z);                         \
        const float w7 = wcalc(AG.a1.w, fsr, AG.g1.w);                         \
        zacc += (w0 + w1) + (w2 + w3) + ((w4 + w5) + (w6 + w7));               \
        uint4 pk;                                                              \
        pk.x = pack_f16(w0, w1); pk.y = pack_f16(w2, w3);                      \
        pk.z = pack_f16(w4, w5); pk.w = pack_f16(w6, w7);                      \
        *reinterpret_cast<uint4*>(smem + (BUF) * ABUF + awo) = pk;             \
    }

#define MFMA_PHASE(BUF, B0, B1, B2, B3)                                        \
    {                                                                          \
        const char* ab_ = smem + (BUF) * ABUF + aro;                           \
        F16V a0v, a1v, a2v, a3v, b0v, b1v, b2v, b3v;                           \
        a0v.u = *reinterpret_cast<const uint4*>(ab_ + (((p * 128 + 0 * 32 + kg8) * 2) ^ fswz)); \
        a1v.u = *reinterpret_cast<const uint4*>(ab_ + (((p * 128 + 1 * 32 + kg8) * 2) ^ fswz)); \
        a2v.u = *reinterpret_cast<const uint4*>(ab_ + (((p * 128 + 2 * 32 + kg8) * 2) ^ fswz)); \
        a3v.u = *reinterpret_cast<const uint4*>(ab_ + (((p * 128 + 3 * 32 + kg8) * 2) ^ fswz)); \
        b0v.u = B0; b1v.u = B1; b2v.u = B2; b3v.u = B3;                        \
        __builtin_amdgcn_s_setprio(1);                                         \
        acc = __builtin_amdgcn_mfma_f32_16x16x32_f16(a0v.h, b0v.h, acc, 0, 0, 0); \
        acc = __builtin_amdgcn_mfma_f32_16x16x32_f16(a1v.h, b1v.h, acc, 0, 0, 0); \
        acc = __builtin_amdgcn_mfma_f32_16x16x32_f16(a2v.h, b2v.h, acc, 0, 0, 0); \
        acc = __builtin_amdgcn_mfma_f32_16x16x32_f16(a3v.h, b3v.h, acc, 0, 0, 0); \
        __builtin_amdgcn_s_setprio(0);                                         \
    }

    // ---- prologue ----
    LOAD_ADJG(0);
    LOAD_B(0, BA0, BA1, BA2, BA3);
    STAGE(0);                  // tile 0 -> buf 0 (consumes AG tile 0)
    LOAD_ADJG(1);
    BAR;

    for (int tt = 0; tt < NTILE; tt += 2) {
        // even: tile tt (buf0, BA)
        if (tt + 1 < NTILE) LOAD_B(tt + 1, BB0, BB1, BB2, BB3);
        MFMA_PHASE(0, BA0, BA1, BA2, BA3);
        {
            STAGE(1);          // tile tt+1 -> buf1 (consumes AG tile tt+1)
            if (tt + 2 < NTILE) LOAD_ADJG(tt + 2);
        }
        BAR;
        // odd: tile tt+1 (buf1, BB)
        if (tt + 2 < NTILE) LOAD_B(tt + 2, BA0, BA1, BA2, BA3);
        MFMA_PHASE(1, BB0, BB1, BB2, BB3);
        if (tt + 2 < NTILE) {
            STAGE(0);          // tile tt+2 -> buf0
            if (tt + 3 < NTILE) LOAD_ADJG(tt + 3);
        }
        BAR;
    }
#undef LOAD_ADJG
#undef LOAD_B
#undef STAGE
#undef MFMA_PHASE
#undef BAR

    __syncthreads();           // drain last MFMA reads before aliasing LDS

    // ---- Z + cross-parity reduction, epilogue ----
    float* zb = reinterpret_cast<float*>(smem + 8192);
    {
        float z = zacc;
#pragma unroll
        for (int off = 1; off < 32; off <<= 1) z += __shfl_xor(z, off, 64);
        if ((l & 31) == 0) zb[srow] = z;
    }
    *reinterpret_cast<f32x4*>(smem + w * 1024 + l * 16) = acc;
    __syncthreads();
#pragma unroll
    for (int e0 = 0; e0 < 2; ++e0) {
        const int e = t + e0 * 512;
        const int rr = e >> 6, f2 = e & 63;
        const int ft2 = f2 >> 4, n = f2 & 15;
        const int ln = n | ((rr >> 2) << 4);
        const int rg = rr & 3;
        const float s =
            *reinterpret_cast<const float*>(smem + ft2 * 1024 + ln * 16 + rg * 4) +
            *reinterpret_cast<const float*>(smem + (ft2 + 4) * 1024 + ln * 16 + rg * 4);
        const float hp = s / zb[rr];
        out[(size_t)(row0 + rr) * FOUT + f2] = hp > 0.f ? hp : expm1f(hp);
    }
}

extern "C" void kernel_launch(void* const* d_in, const int* in_sizes, int n_in,
                              void* d_out, int out_size, void* d_ws, size_t ws_size,
                              hipStream_t stream) {
    const float* h   = (const float*)d_in[0];
    const int*   adj = (const int*)d_in[1];
    const float* W   = (const float*)d_in[2];
    const float* a   = (const float*)d_in[3];
    float* out = (float*)d_out;

    float* ws = (float*)d_ws;
    float* fsrc = ws;
    float* fdst = fsrc + N;
    uint4* Bp = (uint4*)(fdst + N);        // FOUT*N f16 = 1 MB, pre-fragmented

    gat_prep<<<dim3(N / 32), dim3(512), 0, stream>>>(h, W, a, fsrc, fdst, Bp);
    gat_main<<<dim3(N / 16), dim3(512), 0, stream>>>(adj, Bp, fsrc, fdst, out);
}

// Round 11
// 91.673 us; speedup vs baseline: 1.3482x; 1.3482x over previous
//
#include <hip/hip_runtime.h>
#include <math.h>

#define N 8192
#define FIN 256
#define FOUT 64
#define ALPHA 0.2f
#define LOG2E 1.442695040888963f

#define JT 256                    // j-tile columns
#define NTILE (N / JT)            // 32
#define ROWPITCH 512              // bytes per A-LDS row (256 f16)
#define ABUF (16 * ROWPITCH)      // 8192 B per buffer
#define SMEM_BYTES (2 * ABUF)     // 16384

typedef float f32x4 __attribute__((ext_vector_type(4)));
typedef _Float16 f16x8 __attribute__((ext_vector_type(8)));

union F16V { uint4 u; f16x8 h; };

__device__ __forceinline__ unsigned pack_f16(float a, float b) {
    union { _Float16 h; unsigned short u; } ca, cb;
    ca.h = (_Float16)a; cb.h = (_Float16)b;      // v_cvt_f16_f32, RNE
    return (unsigned)ca.u | ((unsigned)cb.u << 16);
}
// w' = exp(leaky(e)) * 2^-4  (scale cancels in softmax ratio; keeps f16 in range)
__device__ __forceinline__ float wcalc(int av, float fsr, float g) {
    float e = fsr + g;
    float le = e > 0.f ? e : ALPHA * e;
    float r = __builtin_exp2f(fmaf(le, LOG2E, -4.0f));
    return av != 0 ? r : 0.f;
}

// ---------------- Kernel 1: Wh = h@W -> fsrc/fdst + B_packed (pre-fragmented f16) ----
// Bp[(chunk*4+ft)*64 + lane] = f16(Wh[chunk*32+(lane>>4)*8+e][ft*16+(lane&15)])
// so gat_main's B-fragment loads are single contiguous 16B/lane segments.
__global__ __launch_bounds__(512) void gat_prep(
    const float* __restrict__ h, const float* __restrict__ W,
    const float* __restrict__ a,
    float* __restrict__ fsrc, float* __restrict__ fdst,
    uint4* __restrict__ Bp)
{
    __shared__ float sWh[32][FOUT + 1];
    const int t = threadIdx.x;
    const int f = t & 63;
    const int wq = t >> 6;                 // 0..7, 4 rows each
    const int row0 = blockIdx.x * 32;
    const int rbase = row0 + wq * 4;

    float acc[4] = {0.f, 0.f, 0.f, 0.f};
    for (int k0 = 0; k0 < FIN; k0 += 4) {
        const float w0 = W[(k0 + 0) * FOUT + f];
        const float w1 = W[(k0 + 1) * FOUT + f];
        const float w2 = W[(k0 + 2) * FOUT + f];
        const float w3 = W[(k0 + 3) * FOUT + f];
#pragma unroll
        for (int rr = 0; rr < 4; ++rr) {
            const float4 hv = *reinterpret_cast<const float4*>(
                &h[(size_t)(rbase + rr) * FIN + k0]);
            acc[rr] = fmaf(hv.x, w0, acc[rr]);
            acc[rr] = fmaf(hv.y, w1, acc[rr]);
            acc[rr] = fmaf(hv.z, w2, acc[rr]);
            acc[rr] = fmaf(hv.w, w3, acc[rr]);
        }
    }
    const float as = a[f], ad = a[FOUT + f];
#pragma unroll
    for (int rr = 0; rr < 4; ++rr) {
        sWh[wq * 4 + rr][f] = acc[rr];
        float fs = acc[rr] * as, fd = acc[rr] * ad;
#pragma unroll
        for (int off = 1; off < 64; off <<= 1) {
            fs += __shfl_xor(fs, off, 64);
            fd += __shfl_xor(fd, off, 64);
        }
        if (f == 0) { fsrc[rbase + rr] = fs; fdst[rbase + rr] = fd; }
    }
    __syncthreads();
    if (t < 256) {
        const int ft = t >> 6;             // 0..3
        const int l = t & 63;
        const int li = l & 15, g = l >> 4;
        float v[8];
#pragma unroll
        for (int e = 0; e < 8; ++e) v[e] = sWh[g * 8 + e][ft * 16 + li];
        uint4 pk;
        pk.x = pack_f16(v[0], v[1]);
        pk.y = pack_f16(v[2], v[3]);
        pk.z = pack_f16(v[4], v[5]);
        pk.w = pack_f16(v[6], v[7]);
        Bp[(size_t)(blockIdx.x * 4 + ft) * 64 + l] = pk;
    }
}

// ---------------- Kernel 2: A-only-LDS MFMA flash softmax-PV ----
// adj read contiguously (R5/R7 lesson), redistributed to A-fragment layout via
// a small dbuf LDS tile; B fragments loaded coalesced from Bp (R8 lesson, no
// LDS). Raw s_barrier + lgkmcnt(0)-only waits -> register prefetches survive
// barriers with counted vmcnt. (512,4): VGPR cap 128 -> no spill (R10 lesson).
struct AdjG { int4 a0, a1; float4 g0, g1; };

__global__ __launch_bounds__(512, 4) void gat_main(
    const int* __restrict__ adj,
    const uint4* __restrict__ Bp,
    const float* __restrict__ fsrc, const float* __restrict__ fdst,
    float* __restrict__ out)
{
    __shared__ __align__(16) char smem[SMEM_BYTES];

    const int t = threadIdx.x;
    const int l = t & 63;
    const int w = t >> 6;
    const int row0 = blockIdx.x * 16;

    // --- staging map (contiguous adj) ---
    const int srow = t >> 5;               // 0..15
    const int sc8 = (t & 31) * 8;          // col (elements)
    const float fsr = fsrc[row0 + srow];
    const size_t adjrow = (size_t)(row0 + srow) * N;
    const int awo = srow * ROWPITCH + (((t & 31) * 16) ^ ((srow & 7) << 4));

    // --- MFMA map ---
    const int ft = w & 3;
    const int p = w >> 2;
    const int r16 = l & 15;
    const int kg8 = (l >> 4) << 3;
    const int fswz = (r16 & 7) << 4;
    const int aro = r16 * ROWPITCH;
    // Bp index (uint4): tile*2048 + p*1024 + ks*256 + ft*64 + lane
    const uint4* Bq = Bp + (size_t)p * 1024 + ft * 64 + l;

    f32x4 acc = {0.f, 0.f, 0.f, 0.f};
    float zacc = 0.f;
    AdjG AG;
    uint4 BA0, BA1, BA2, BA3, BB0, BB1, BB2, BB3;

#define BAR                                                                    \
    {                                                                          \
        asm volatile("s_waitcnt lgkmcnt(0)" ::: "memory");                     \
        __builtin_amdgcn_s_barrier();                                          \
    }

#define LOAD_ADJG(tile)                                                        \
    {                                                                          \
        const int j0_ = (tile) * JT;                                           \
        AG.a0 = *reinterpret_cast<const int4*>(&adj[adjrow + j0_ + sc8]);      \
        AG.a1 = *reinterpret_cast<const int4*>(&adj[adjrow + j0_ + sc8 + 4]);  \
        AG.g0 = *reinterpret_cast<const float4*>(&fdst[j0_ + sc8]);            \
        AG.g1 = *reinterpret_cast<const float4*>(&fdst[j0_ + sc8 + 4]);        \
    }

#define LOAD_B(tile, B0, B1, B2, B3)                                           \
    {                                                                          \
        const uint4* bq_ = Bq + (size_t)(tile) * 2048;                         \
        B0 = bq_[0];                                                           \
        B1 = bq_[256];                                                         \
        B2 = bq_[512];                                                         \
        B3 = bq_[768];                                                         \
    }

#define STAGE(BUF)                                                             \
    {                                                                          \
        const float w0 = wcalc(AG.a0.x, fsr, AG.g0.x);                         \
        const float w1 = wcalc(AG.a0.y, fsr, AG.g0.y);                         \
        const float w2 = wcalc(AG.a0.z, fsr, AG.g0.z);                         \
        const float w3 = wcalc(AG.a0.w, fsr, AG.g0.w);                         \
        const float w4 = wcalc(AG.a1.x, fsr, AG.g1.x);                         \
        const float w5 = wcalc(AG.a1.y, fsr, AG.g1.y);                         \
        const float w6 = wcalc(AG.a1.z, fsr, AG.g1.z);                         \
        const float w7 = wcalc(AG.a1.w, fsr, AG.g1.w);                         \
        zacc += (w0 + w1) + (w2 + w3) + ((w4 + w5) + (w6 + w7));               \
        uint4 pk;                                                              \
        pk.x = pack_f16(w0, w1); pk.y = pack_f16(w2, w3);                      \
        pk.z = pack_f16(w4, w5); pk.w = pack_f16(w6, w7);                      \
        *reinterpret_cast<uint4*>(smem + (BUF) * ABUF + awo) = pk;             \
    }

#define MFMA_PHASE(BUF, B0, B1, B2, B3)                                        \
    {                                                                          \
        const char* ab_ = smem + (BUF) * ABUF + aro;                           \
        F16V a0v, a1v, a2v, a3v, b0v, b1v, b2v, b3v;                           \
        a0v.u = *reinterpret_cast<const uint4*>(ab_ + (((p * 128 + 0 * 32 + kg8) * 2) ^ fswz)); \
        a1v.u = *reinterpret_cast<const uint4*>(ab_ + (((p * 128 + 1 * 32 + kg8) * 2) ^ fswz)); \
        a2v.u = *reinterpret_cast<const uint4*>(ab_ + (((p * 128 + 2 * 32 + kg8) * 2) ^ fswz)); \
        a3v.u = *reinterpret_cast<const uint4*>(ab_ + (((p * 128 + 3 * 32 + kg8) * 2) ^ fswz)); \
        b0v.u = B0; b1v.u = B1; b2v.u = B2; b3v.u = B3;                        \
        __builtin_amdgcn_s_setprio(1);                                         \
        acc = __builtin_amdgcn_mfma_f32_16x16x32_f16(a0v.h, b0v.h, acc, 0, 0, 0); \
        acc = __builtin_amdgcn_mfma_f32_16x16x32_f16(a1v.h, b1v.h, acc, 0, 0, 0); \
        acc = __builtin_amdgcn_mfma_f32_16x16x32_f16(a2v.h, b2v.h, acc, 0, 0, 0); \
        acc = __builtin_amdgcn_mfma_f32_16x16x32_f16(a3v.h, b3v.h, acc, 0, 0, 0); \
        __builtin_amdgcn_s_setprio(0);                                         \
    }

    // ---- prologue ----
    LOAD_ADJG(0);
    LOAD_B(0, BA0, BA1, BA2, BA3);
    STAGE(0);                  // tile 0 -> buf 0 (consumes AG tile 0)
    LOAD_ADJG(1);
    BAR;

    for (int tt = 0; tt < NTILE; tt += 2) {
        // even: tile tt (buf0, BA)
        if (tt + 1 < NTILE) LOAD_B(tt + 1, BB0, BB1, BB2, BB3);
        MFMA_PHASE(0, BA0, BA1, BA2, BA3);
        {
            STAGE(1);          // tile tt+1 -> buf1 (consumes AG tile tt+1)
            if (tt + 2 < NTILE) LOAD_ADJG(tt + 2);
        }
        BAR;
        // odd: tile tt+1 (buf1, BB)
        if (tt + 2 < NTILE) LOAD_B(tt + 2, BA0, BA1, BA2, BA3);
        MFMA_PHASE(1, BB0, BB1, BB2, BB3);
        if (tt + 2 < NTILE) {
            STAGE(0);          // tile tt+2 -> buf0
            if (tt + 3 < NTILE) LOAD_ADJG(tt + 3);
        }
        BAR;
    }
#undef LOAD_ADJG
#undef LOAD_B
#undef STAGE
#undef MFMA_PHASE
#undef BAR

    __syncthreads();           // drain last MFMA reads before aliasing LDS

    // ---- Z + cross-parity reduction, epilogue ----
    float* zb = reinterpret_cast<float*>(smem + 8192);
    {
        float z = zacc;
#pragma unroll
        for (int off = 1; off < 32; off <<= 1) z += __shfl_xor(z, off, 64);
        if ((l & 31) == 0) zb[srow] = z;
    }
    *reinterpret_cast<f32x4*>(smem + w * 1024 + l * 16) = acc;
    __syncthreads();
#pragma unroll
    for (int e0 = 0; e0 < 2; ++e0) {
        const int e = t + e0 * 512;
        const int rr = e >> 6, f2 = e & 63;
        const int ft2 = f2 >> 4, n = f2 & 15;
        const int ln = n | ((rr >> 2) << 4);
        const int rg = rr & 3;
        const float s =
            *reinterpret_cast<const float*>(smem + ft2 * 1024 + ln * 16 + rg * 4) +
            *reinterpret_cast<const float*>(smem + (ft2 + 4) * 1024 + ln * 16 + rg * 4);
        const float hp = s / zb[rr];
        out[(size_t)(row0 + rr) * FOUT + f2] = hp > 0.f ? hp : expm1f(hp);
    }
}

extern "C" void kernel_launch(void* const* d_in, const int* in_sizes, int n_in,
                              void* d_out, int out_size, void* d_ws, size_t ws_size,
                              hipStream_t stream) {
    const float* h   = (const float*)d_in[0];
    const int*   adj = (const int*)d_in[1];
    const float* W   = (const float*)d_in[2];
    const float* a   = (const float*)d_in[3];
    float* out = (float*)d_out;

    float* ws = (float*)d_ws;
    float* fsrc = ws;
    float* fdst = fsrc + N;
    uint4* Bp = (uint4*)(fdst + N);        // FOUT*N f16 = 1 MB, pre-fragmented

    gat_prep<<<dim3(N / 32), dim3(512), 0, stream>>>(h, W, a, fsrc, fdst, Bp);
    gat_main<<<dim3(N / 16), dim3(512), 0, stream>>>(adj, Bp, fsrc, fdst, out);
}